// Round 1
// baseline (311.857 us; speedup 1.0000x reference)
//
#include <hip/hip_runtime.h>
#include <hip/hip_bf16.h>

// ContrastiveLoss: z (8192x1024 fp32) -> scalar
//   zn = z / max(||z||,eps); S = zn@zn^T; diag=MASK; /T; nll = -S[i,i^4096] + lse(S[i,:]); mean
// Strategy: fixed-shift logsumexp (logits <= C=1/T) => partial exp-sums are plain sums,
// combinable via atomicAdd across column-tile blocks. bf16 MFMA GEMM, never materialize S.

#define N 8192
#define D 1024
#define INV_T 14.285714285714286f

typedef __bf16 bf16x8 __attribute__((ext_vector_type(8)));
typedef float f32x4 __attribute__((ext_vector_type(4)));

__device__ inline void gload16(const void* g, void* l) {
  __builtin_amdgcn_global_load_lds(
      (const __attribute__((address_space(1))) void*)g,
      (__attribute__((address_space(3))) void*)l, 16, 0, 0);
}

__device__ inline unsigned short f32_to_bf16(float f) {
  unsigned int u = __float_as_uint(f);
  unsigned int r = (u + 0x7FFFu + ((u >> 16) & 1u)) >> 16;  // RNE
  return (unsigned short)r;
}

// Phase 1: row-normalize z, cast to bf16, store to ws. One block per row.
__global__ __launch_bounds__(256) void k_normalize(const float* __restrict__ z,
                                                   unsigned short* __restrict__ zn) {
  const int row = blockIdx.x;
  const int t = threadIdx.x;
  const float4 v = ((const float4*)(z + (size_t)row * D))[t];
  float ss = v.x * v.x + v.y * v.y + v.z * v.z + v.w * v.w;
#pragma unroll
  for (int off = 32; off > 0; off >>= 1) ss += __shfl_down(ss, off, 64);
  __shared__ float red[4];
  __shared__ float s_inv;
  if ((t & 63) == 0) red[t >> 6] = ss;
  __syncthreads();
  if (t == 0) {
    float tot = red[0] + red[1] + red[2] + red[3];
    s_inv = 1.0f / fmaxf(sqrtf(tot), 1e-8f);
  }
  __syncthreads();
  const float inv = s_inv;
  ushort4 o;
  o.x = f32_to_bf16(v.x * inv);
  o.y = f32_to_bf16(v.y * inv);
  o.z = f32_to_bf16(v.z * inv);
  o.w = f32_to_bf16(v.w * inv);
  ((ushort4*)(zn + (size_t)row * D))[t] = o;
}

// Phase 2: one 128x128 tile of S per block; fused exp + per-row partial sums.
// 256 threads = 4 waves in 2x2; each wave does 64x64 via 4x4 of 16x16x32 bf16 MFMA.
// BK=64: LDS A 128x64 bf16 (16KB) + B 16KB. 16B-chunk XOR swizzle (c ^= row&7)
// kills ds_read_b128 bank conflicts while keeping global_load_lds slot order.
__global__ __launch_bounds__(256) void k_tile(const unsigned short* __restrict__ zn,
                                              float* __restrict__ rowsum,
                                              float* __restrict__ pos) {
  __shared__ __align__(16) char smem[32768];
  const int tid = threadIdx.x;
  const int w = tid >> 6, l = tid & 63;
  const int tr = blockIdx.x >> 6, tc = blockIdx.x & 63;
  const int wr = w >> 1, wc = w & 1;
  const int m = l & 15, kg = l >> 4;  // frag row/col index, k-group
  const int rowA0 = tr * 128, colB0 = tc * 128;

  f32x4 acc[4][4] = {};

  // staging slot -> (row, swizzled chunk col), slot s = j*256 + tid, 1024 slots/tile
  int srow[4], scol[4];
#pragma unroll
  for (int j = 0; j < 4; ++j) {
    int s = j * 256 + tid;
    int r = s >> 3, cp = s & 7;
    srow[j] = r;
    scol[j] = cp ^ (r & 7);
  }

  for (int kt = 0; kt < 16; ++kt) {
    const size_t kbyte = (size_t)kt * 128;  // 64 bf16 per K-step
#pragma unroll
    for (int j = 0; j < 4; ++j) {
      const char* gA = (const char*)zn + ((size_t)(rowA0 + srow[j]) * 2048 + kbyte + scol[j] * 16);
      gload16(gA, smem + (j * 256 + w * 64) * 16);
      const char* gB = (const char*)zn + ((size_t)(colB0 + srow[j]) * 2048 + kbyte + scol[j] * 16);
      gload16(gB, smem + 16384 + (j * 256 + w * 64) * 16);
    }
    __syncthreads();
#pragma unroll
    for (int ks = 0; ks < 2; ++ks) {
      bf16x8 af[4], bfr[4];
      const int csw = ((ks * 4 + kg) ^ (m & 7)) * 16;
#pragma unroll
      for (int mt = 0; mt < 4; ++mt)
        af[mt] = *(const bf16x8*)(smem + (wr * 64 + mt * 16 + m) * 128 + csw);
#pragma unroll
      for (int nt = 0; nt < 4; ++nt)
        bfr[nt] = *(const bf16x8*)(smem + 16384 + (wc * 64 + nt * 16 + m) * 128 + csw);
#pragma unroll
      for (int mt = 0; mt < 4; ++mt)
#pragma unroll
        for (int nt = 0; nt < 4; ++nt)
          acc[mt][nt] = __builtin_amdgcn_mfma_f32_16x16x32_bf16(af[mt], bfr[nt], acc[mt][nt], 0, 0, 0);
    }
    __syncthreads();
  }

  // Epilogue: C/D layout col=l&15, row=(l>>4)*4+reg. Fixed-shift exp, row-sum
  // across the 16 col-lanes (shuffle-xor), atomicAdd into global rowsum.
  const int quad = l >> 4;
  const int col = l & 15;
#pragma unroll
  for (int mt = 0; mt < 4; ++mt) {
    float rs[4] = {0.f, 0.f, 0.f, 0.f};
#pragma unroll
    for (int nt = 0; nt < 4; ++nt) {
      const int gcol = colB0 + wc * 64 + nt * 16 + col;
#pragma unroll
      for (int r = 0; r < 4; ++r) {
        const int grow = rowA0 + wr * 64 + mt * 16 + quad * 4 + r;
        const float t = acc[mt][nt][r] * INV_T;
        if (gcol == (grow ^ (N / 2))) pos[grow] = t;          // unique writer
        rs[r] += (gcol == grow) ? 0.0f : __expf(t - INV_T);   // diag masked
      }
    }
#pragma unroll
    for (int off = 1; off < 16; off <<= 1) {
#pragma unroll
      for (int r = 0; r < 4; ++r) rs[r] += __shfl_xor(rs[r], off, 64);
    }
    if (col == 0) {
#pragma unroll
      for (int r = 0; r < 4; ++r)
        atomicAdd(&rowsum[rowA0 + wr * 64 + mt * 16 + quad * 4 + r], rs[r]);
    }
  }
}

// Phase 3: nll_i = -pos_i + C + log(rowsum_i); out = mean.
__global__ __launch_bounds__(256) void k_final(const float* __restrict__ rowsum,
                                               const float* __restrict__ pos,
                                               float* __restrict__ out) {
  const int t = threadIdx.x;
  float s = 0.f;
  for (int i = t; i < N; i += 256) s += INV_T + __logf(rowsum[i]) - pos[i];
#pragma unroll
  for (int off = 32; off > 0; off >>= 1) s += __shfl_down(s, off, 64);
  __shared__ float red[4];
  if ((t & 63) == 0) red[t >> 6] = s;
  __syncthreads();
  if (t == 0) out[0] = (red[0] + red[1] + red[2] + red[3]) * (1.0f / N);
}

extern "C" void kernel_launch(void* const* d_in, const int* in_sizes, int n_in,
                              void* d_out, int out_size, void* d_ws, size_t ws_size,
                              hipStream_t stream) {
  const float* z = (const float*)d_in[0];
  float* out = (float*)d_out;
  char* ws = (char*)d_ws;
  unsigned short* zn = (unsigned short*)ws;                       // 16 MiB bf16
  float* rowsum = (float*)(ws + (size_t)N * D * 2);               // 32 KiB
  float* pos = (float*)(ws + (size_t)N * D * 2 + (size_t)N * 4);  // 32 KiB

  hipMemsetAsync(rowsum, 0, (size_t)N * sizeof(float), stream);
  k_normalize<<<N, 256, 0, stream>>>(z, zn);
  k_tile<<<(N / 128) * (N / 128), 256, 0, stream>>>(zn, rowsum, pos);
  k_final<<<1, 256, 0, stream>>>(rowsum, pos, out);
}

// Round 2
// 198.019 us; speedup vs baseline: 1.5749x; 1.5749x over previous
//
#include <hip/hip_runtime.h>
#include <hip/hip_bf16.h>

// ContrastiveLoss: z (8192x1024 fp32) -> scalar
//   zn = z / max(||z||,eps); S = zn@zn^T; diag=MASK; /T; nll = -S[i,i^4096] + lse(S[i,:]); mean
// R2: exploit symmetry — only lower-triangle 128x128 tiles (2080 of 4096).
// Off-diag tile (tr,tc) contributes row-sums for block tr (sum over cols) AND
// row-sums for block tc (= its col sums, by symmetry). Fixed-shift logsumexp
// (logits <= C=1/T) => partials are plain sums, combined via atomicAdd.

#define N 8192
#define D 1024
#define INV_T 14.285714285714286f

typedef __bf16 bf16x8 __attribute__((ext_vector_type(8)));
typedef float f32x4 __attribute__((ext_vector_type(4)));

__device__ inline void gload16(const void* g, void* l) {
  __builtin_amdgcn_global_load_lds(
      (const __attribute__((address_space(1))) void*)g,
      (__attribute__((address_space(3))) void*)l, 16, 0, 0);
}

__device__ inline unsigned short f32_to_bf16(float f) {
  unsigned int u = __float_as_uint(f);
  unsigned int r = (u + 0x7FFFu + ((u >> 16) & 1u)) >> 16;  // RNE
  return (unsigned short)r;
}

// Phase 1: row-normalize z, cast to bf16, store to ws. One block per row.
__global__ __launch_bounds__(256) void k_normalize(const float* __restrict__ z,
                                                   unsigned short* __restrict__ zn) {
  const int row = blockIdx.x;
  const int t = threadIdx.x;
  const float4 v = ((const float4*)(z + (size_t)row * D))[t];
  float ss = v.x * v.x + v.y * v.y + v.z * v.z + v.w * v.w;
#pragma unroll
  for (int off = 32; off > 0; off >>= 1) ss += __shfl_down(ss, off, 64);
  __shared__ float red[4];
  __shared__ float s_inv;
  if ((t & 63) == 0) red[t >> 6] = ss;
  __syncthreads();
  if (t == 0) {
    float tot = red[0] + red[1] + red[2] + red[3];
    s_inv = 1.0f / fmaxf(sqrtf(tot), 1e-8f);
  }
  __syncthreads();
  const float inv = s_inv;
  ushort4 o;
  o.x = f32_to_bf16(v.x * inv);
  o.y = f32_to_bf16(v.y * inv);
  o.z = f32_to_bf16(v.z * inv);
  o.w = f32_to_bf16(v.w * inv);
  ((ushort4*)(zn + (size_t)row * D))[t] = o;
}

// Phase 2: lower-triangle 128x128 tiles. 256 threads = 4 waves in 2x2; each
// wave 64x64 via 4x4 of 16x16x32 bf16 MFMA. BK=64, LDS 2x16KB, 16B-chunk XOR
// swizzle (c ^= row&7) for conflict-free ds_read_b128 with in-order
// global_load_lds slots. Epilogue: exp + row-sums (16 col-lanes shuffle) and,
// for off-diag tiles, col-sums (quad shuffle) -> atomicAdd into rowsum.
__global__ __launch_bounds__(256) void k_tile(const unsigned short* __restrict__ zn,
                                              float* __restrict__ rowsum,
                                              float* __restrict__ pos) {
  __shared__ __align__(16) char smem[32768];
  const int tid = threadIdx.x;
  const int w = tid >> 6, l = tid & 63;

  // decode blockIdx -> lower-triangle (tr, tc), tr >= tc
  const int b = blockIdx.x;
  int tr = (int)((sqrtf(8.0f * (float)b + 1.0f) - 1.0f) * 0.5f);
  if (tr * (tr + 1) / 2 > b) --tr;
  if ((tr + 1) * (tr + 2) / 2 <= b) ++tr;
  const int tc = b - tr * (tr + 1) / 2;
  const bool diag = (tr == tc);

  const int wr = w >> 1, wc = w & 1;
  const int m = l & 15, kg = l >> 4;
  const int rowA0 = tr * 128, colB0 = tc * 128;

  f32x4 acc[4][4] = {};

  int srow[4], scol[4];
#pragma unroll
  for (int j = 0; j < 4; ++j) {
    int s = j * 256 + tid;
    int r = s >> 3, cp = s & 7;
    srow[j] = r;
    scol[j] = cp ^ (r & 7);
  }

  char* const bbase = diag ? smem : (smem + 16384);  // diag: B frags read from A tile

  for (int kt = 0; kt < 16; ++kt) {
    const size_t kbyte = (size_t)kt * 128;  // 64 bf16 per K-step
#pragma unroll
    for (int j = 0; j < 4; ++j) {
      const char* gA = (const char*)zn + ((size_t)(rowA0 + srow[j]) * 2048 + kbyte + scol[j] * 16);
      gload16(gA, smem + (j * 256 + w * 64) * 16);
    }
    if (!diag) {
#pragma unroll
      for (int j = 0; j < 4; ++j) {
        const char* gB = (const char*)zn + ((size_t)(colB0 + srow[j]) * 2048 + kbyte + scol[j] * 16);
        gload16(gB, smem + 16384 + (j * 256 + w * 64) * 16);
      }
    }
    __syncthreads();
#pragma unroll
    for (int ks = 0; ks < 2; ++ks) {
      bf16x8 af[4], bfr[4];
      const int csw = ((ks * 4 + kg) ^ (m & 7)) * 16;
#pragma unroll
      for (int mt = 0; mt < 4; ++mt)
        af[mt] = *(const bf16x8*)(smem + (wr * 64 + mt * 16 + m) * 128 + csw);
#pragma unroll
      for (int nt = 0; nt < 4; ++nt)
        bfr[nt] = *(const bf16x8*)(bbase + (wc * 64 + nt * 16 + m) * 128 + csw);
#pragma unroll
      for (int mt = 0; mt < 4; ++mt)
#pragma unroll
        for (int nt = 0; nt < 4; ++nt)
          acc[mt][nt] = __builtin_amdgcn_mfma_f32_16x16x32_bf16(af[mt], bfr[nt], acc[mt][nt], 0, 0, 0);
    }
    __syncthreads();
  }

  // Epilogue. C/D layout: col=l&15, row=(l>>4)*4+reg.
  const int quad = l >> 4;
  const int col = l & 15;
  float cs[4] = {0.f, 0.f, 0.f, 0.f};  // column partial sums (this lane's quad rows)
#pragma unroll
  for (int mt = 0; mt < 4; ++mt) {
    float rs[4] = {0.f, 0.f, 0.f, 0.f};
#pragma unroll
    for (int nt = 0; nt < 4; ++nt) {
      const int gcol = colB0 + wc * 64 + nt * 16 + col;
#pragma unroll
      for (int r = 0; r < 4; ++r) {
        const int grow = rowA0 + wr * 64 + mt * 16 + quad * 4 + r;
        const float t = acc[mt][nt][r] * INV_T;
        if (gcol == (grow ^ (N / 2))) {  // pos pair; only in tiles tc == tr^32
          pos[grow] = t;
          pos[gcol] = t;  // S symmetric
        }
        const float e = (gcol == grow) ? 0.0f : __expf(t - INV_T);
        rs[r] += e;
        cs[nt] += e;
      }
    }
#pragma unroll
    for (int off = 1; off < 16; off <<= 1) {
#pragma unroll
      for (int r = 0; r < 4; ++r) rs[r] += __shfl_xor(rs[r], off, 64);
    }
    if (col == 0) {
#pragma unroll
      for (int r = 0; r < 4; ++r)
        atomicAdd(&rowsum[rowA0 + wr * 64 + mt * 16 + quad * 4 + r], rs[r]);
    }
  }
  if (!diag) {  // col sums = row-sums for block tc rows (symmetry)
#pragma unroll
    for (int nt = 0; nt < 4; ++nt) {
      cs[nt] += __shfl_xor(cs[nt], 16, 64);
      cs[nt] += __shfl_xor(cs[nt], 32, 64);
    }
    if (l < 16) {
#pragma unroll
      for (int nt = 0; nt < 4; ++nt)
        atomicAdd(&rowsum[colB0 + wc * 64 + nt * 16 + l], cs[nt]);
    }
  }
}

// Phase 3: nll_i = -pos_i + C + log(rowsum_i); out = mean via block partials + atomicAdd.
__global__ __launch_bounds__(256) void k_final(const float* __restrict__ rowsum,
                                               const float* __restrict__ pos,
                                               float* __restrict__ out) {
  const int t = threadIdx.x;
  const int i = blockIdx.x * 256 + t;
  float s = INV_T + __logf(rowsum[i]) - pos[i];
#pragma unroll
  for (int off = 32; off > 0; off >>= 1) s += __shfl_down(s, off, 64);
  __shared__ float red[4];
  if ((t & 63) == 0) red[t >> 6] = s;
  __syncthreads();
  if (t == 0) atomicAdd(out, (red[0] + red[1] + red[2] + red[3]) * (1.0f / N));
}

extern "C" void kernel_launch(void* const* d_in, const int* in_sizes, int n_in,
                              void* d_out, int out_size, void* d_ws, size_t ws_size,
                              hipStream_t stream) {
  const float* z = (const float*)d_in[0];
  float* out = (float*)d_out;
  char* ws = (char*)d_ws;
  unsigned short* zn = (unsigned short*)ws;                       // 16 MiB bf16
  float* rowsum = (float*)(ws + (size_t)N * D * 2);               // 32 KiB
  float* pos = (float*)(ws + (size_t)N * D * 2 + (size_t)N * 4);  // 32 KiB

  hipMemsetAsync(rowsum, 0, (size_t)N * sizeof(float), stream);
  hipMemsetAsync(out, 0, sizeof(float), stream);
  k_normalize<<<N, 256, 0, stream>>>(z, zn);
  const int ntiles = (N / 128) * (N / 128 + 1) / 2;  // 2080 lower-triangle tiles
  k_tile<<<ntiles, 256, 0, stream>>>(zn, rowsum, pos);
  k_final<<<N / 256, 256, 0, stream>>>(rowsum, pos, out);
}

// Round 3
// 175.083 us; speedup vs baseline: 1.7812x; 1.1310x over previous
//
#include <hip/hip_runtime.h>
#include <hip/hip_bf16.h>

// ContrastiveLoss: z (8192x1024 fp32) -> scalar
//   zn = z / max(||z||,eps); S = zn@zn^T; diag=MASK; /T; nll = -S[i,i^4096] + lse(S[i,:]); mean
// R3: 256x256 tiles (512 thr, 8 waves), lower-triangle only, double-buffered
// BK=32 staging (64KB LDS) with prefetch-next-during-MFMA to hide load latency.
// Fixed-shift logsumexp (logits <= C=1/T) => partials combine via atomicAdd.

#define N 8192
#define D 1024
#define INV_T 14.285714285714286f

typedef __bf16 bf16x8 __attribute__((ext_vector_type(8)));
typedef float f32x4 __attribute__((ext_vector_type(4)));

__device__ inline void gload16(const void* g, void* l) {
  __builtin_amdgcn_global_load_lds(
      (const __attribute__((address_space(1))) void*)g,
      (__attribute__((address_space(3))) void*)l, 16, 0, 0);
}

__device__ inline unsigned short f32_to_bf16(float f) {
  unsigned int u = __float_as_uint(f);
  unsigned int r = (u + 0x7FFFu + ((u >> 16) & 1u)) >> 16;  // RNE
  return (unsigned short)r;
}

// Phase 1: row-normalize z, cast to bf16, store to ws. One block per row.
__global__ __launch_bounds__(256) void k_normalize(const float* __restrict__ z,
                                                   unsigned short* __restrict__ zn) {
  const int row = blockIdx.x;
  const int t = threadIdx.x;
  const float4 v = ((const float4*)(z + (size_t)row * D))[t];
  float ss = v.x * v.x + v.y * v.y + v.z * v.z + v.w * v.w;
#pragma unroll
  for (int off = 32; off > 0; off >>= 1) ss += __shfl_down(ss, off, 64);
  __shared__ float red[4];
  __shared__ float s_inv;
  if ((t & 63) == 0) red[t >> 6] = ss;
  __syncthreads();
  if (t == 0) {
    float tot = red[0] + red[1] + red[2] + red[3];
    s_inv = 1.0f / fmaxf(sqrtf(tot), 1e-8f);
  }
  __syncthreads();
  const float inv = s_inv;
  ushort4 o;
  o.x = f32_to_bf16(v.x * inv);
  o.y = f32_to_bf16(v.y * inv);
  o.z = f32_to_bf16(v.z * inv);
  o.w = f32_to_bf16(v.w * inv);
  ((ushort4*)(zn + (size_t)row * D))[t] = o;
}

// Phase 2: 256x256 lower-triangle tile per block. 8 waves: wr=w>>1 (64-row band),
// wc=w&1 (128-col band); per wave 4x8 frags of 16x16x32 bf16 MFMA (acc 128 VGPR).
// BK=32: per buffer A 16KB + B 16KB; two buffers = 64KB LDS. Row stride 64B makes
// each 16-row fragment a contiguous 1KB block -> conflict-free ds_read_b128, and
// global_load_lds slots are plain row-major (no swizzle needed).
__global__ __launch_bounds__(512, 2) void k_tile(const unsigned short* __restrict__ zn,
                                                 float* __restrict__ rowsum,
                                                 float* __restrict__ pos) {
  __shared__ __align__(16) char smem[65536];
  const int tid = threadIdx.x;
  const int w = tid >> 6, l = tid & 63;

  // decode blockIdx -> lower-triangle (tr, tc), tr >= tc, over 32x32 tile grid
  const int b = blockIdx.x;
  int tr = (int)((sqrtf(8.0f * (float)b + 1.0f) - 1.0f) * 0.5f);
  if (tr * (tr + 1) / 2 > b) --tr;
  if ((tr + 1) * (tr + 2) / 2 <= b) ++tr;
  const int tc = b - tr * (tr + 1) / 2;
  const bool diag = (tr == tc);

  const int wr = w >> 1, wc = w & 1;
  const int m = l & 15, kg = l >> 4;
  const int rowA0 = tr * 256, colB0 = tc * 256;

  f32x4 acc[4][8] = {};

  // staging slot s (0..1023 per matrix): r = s>>2, chunk c = s&3; LDS off = s*16
  const int s0 = tid, s1 = 512 + tid;

  // prologue: stage kt=0 into buffer 0
  {
    const char* base = (const char*)zn;
    char* ab = smem;
    gload16(base + ((size_t)(rowA0 + (s0 >> 2)) * 2048 + (s0 & 3) * 16), ab + s0 * 16);
    gload16(base + ((size_t)(rowA0 + (s1 >> 2)) * 2048 + (s1 & 3) * 16), ab + s1 * 16);
    if (!diag) {
      char* bb = smem + 16384;
      gload16(base + ((size_t)(colB0 + (s0 >> 2)) * 2048 + (s0 & 3) * 16), bb + s0 * 16);
      gload16(base + ((size_t)(colB0 + (s1 >> 2)) * 2048 + (s1 & 3) * 16), bb + s1 * 16);
    }
  }
  __syncthreads();

  for (int kt = 0; kt < 32; ++kt) {
    const int p = kt & 1;
    if (kt < 31) {  // prefetch kt+1 into other buffer (async; overlaps MFMA below)
      const size_t kb = (size_t)(kt + 1) * 64;
      char* ab = smem + (p ^ 1) * 32768;
      gload16((const char*)zn + ((size_t)(rowA0 + (s0 >> 2)) * 2048 + kb + (s0 & 3) * 16), ab + s0 * 16);
      gload16((const char*)zn + ((size_t)(rowA0 + (s1 >> 2)) * 2048 + kb + (s1 & 3) * 16), ab + s1 * 16);
      if (!diag) {
        char* bb = ab + 16384;
        gload16((const char*)zn + ((size_t)(colB0 + (s0 >> 2)) * 2048 + kb + (s0 & 3) * 16), bb + s0 * 16);
        gload16((const char*)zn + ((size_t)(colB0 + (s1 >> 2)) * 2048 + kb + (s1 & 3) * 16), bb + s1 * 16);
      }
    }
    const char* ab = smem + p * 32768;
    const char* bb = diag ? ab : (ab + 16384);
    bf16x8 af[4], bfr[8];
#pragma unroll
    for (int mt = 0; mt < 4; ++mt)
      af[mt] = *(const bf16x8*)(ab + (wr * 64 + mt * 16 + m) * 64 + kg * 16);
#pragma unroll
    for (int nt = 0; nt < 8; ++nt)
      bfr[nt] = *(const bf16x8*)(bb + (wc * 128 + nt * 16 + m) * 64 + kg * 16);
#pragma unroll
    for (int mt = 0; mt < 4; ++mt)
#pragma unroll
      for (int nt = 0; nt < 8; ++nt)
        acc[mt][nt] = __builtin_amdgcn_mfma_f32_16x16x32_bf16(af[mt], bfr[nt], acc[mt][nt], 0, 0, 0);
    __syncthreads();  // drains prefetch (vmcnt) + guards buffer reuse
  }

  // Epilogue. C/D layout: col=l&15, row=(l>>4)*4+reg.
  const int quad = l >> 4;
  const int col = l & 15;
  float cs[8] = {0.f, 0.f, 0.f, 0.f, 0.f, 0.f, 0.f, 0.f};
#pragma unroll
  for (int mt = 0; mt < 4; ++mt) {
    float rs[4] = {0.f, 0.f, 0.f, 0.f};
#pragma unroll
    for (int nt = 0; nt < 8; ++nt) {
      const int gcol = colB0 + wc * 128 + nt * 16 + col;
#pragma unroll
      for (int r = 0; r < 4; ++r) {
        const int grow = rowA0 + wr * 64 + mt * 16 + quad * 4 + r;
        const float t = acc[mt][nt][r] * INV_T;
        if (gcol == (grow ^ (N / 2))) {  // pos pair; never in diag tiles
          pos[grow] = t;
          pos[gcol] = t;  // S symmetric
        }
        const float e = (gcol == grow) ? 0.0f : __expf(t - INV_T);
        rs[r] += e;
        cs[nt] += e;
      }
    }
#pragma unroll
    for (int off = 1; off < 16; off <<= 1) {
#pragma unroll
      for (int r = 0; r < 4; ++r) rs[r] += __shfl_xor(rs[r], off, 64);
    }
    if (col == 0) {
#pragma unroll
      for (int r = 0; r < 4; ++r)
        atomicAdd(&rowsum[rowA0 + wr * 64 + mt * 16 + quad * 4 + r], rs[r]);
    }
  }
  if (!diag) {  // col sums = row-sums for block tc rows (symmetry)
#pragma unroll
    for (int nt = 0; nt < 8; ++nt) {
      cs[nt] += __shfl_xor(cs[nt], 16, 64);
      cs[nt] += __shfl_xor(cs[nt], 32, 64);
    }
    if (l < 16) {
#pragma unroll
      for (int nt = 0; nt < 8; ++nt)
        atomicAdd(&rowsum[colB0 + wc * 128 + nt * 16 + l], cs[nt]);
    }
  }
}

// Phase 3: nll_i = -pos_i + C + log(rowsum_i); out = mean via block partials + atomicAdd.
__global__ __launch_bounds__(256) void k_final(const float* __restrict__ rowsum,
                                               const float* __restrict__ pos,
                                               float* __restrict__ out) {
  const int t = threadIdx.x;
  const int i = blockIdx.x * 256 + t;
  float s = INV_T + __logf(rowsum[i]) - pos[i];
#pragma unroll
  for (int off = 32; off > 0; off >>= 1) s += __shfl_down(s, off, 64);
  __shared__ float red[4];
  if ((t & 63) == 0) red[t >> 6] = s;
  __syncthreads();
  if (t == 0) atomicAdd(out, (red[0] + red[1] + red[2] + red[3]) * (1.0f / N));
}

extern "C" void kernel_launch(void* const* d_in, const int* in_sizes, int n_in,
                              void* d_out, int out_size, void* d_ws, size_t ws_size,
                              hipStream_t stream) {
  const float* z = (const float*)d_in[0];
  float* out = (float*)d_out;
  char* ws = (char*)d_ws;
  unsigned short* zn = (unsigned short*)ws;                       // 16 MiB bf16
  float* rowsum = (float*)(ws + (size_t)N * D * 2);               // 32 KiB
  float* pos = (float*)(ws + (size_t)N * D * 2 + (size_t)N * 4);  // 32 KiB

  hipMemsetAsync(rowsum, 0, (size_t)N * sizeof(float), stream);
  hipMemsetAsync(out, 0, sizeof(float), stream);
  k_normalize<<<N, 256, 0, stream>>>(z, zn);
  const int ntiles = (N / 256) * (N / 256 + 1) / 2;  // 528 lower-triangle tiles
  k_tile<<<ntiles, 512, 0, stream>>>(zn, rowsum, pos);
  k_final<<<N / 256, 256, 0, stream>>>(rowsum, pos, out);
}

// Round 4
// 163.957 us; speedup vs baseline: 1.9021x; 1.0679x over previous
//
#include <hip/hip_runtime.h>
#include <hip/hip_bf16.h>

// ContrastiveLoss: z (8192x1024 fp32) -> scalar
//   zn = z / max(||z||,eps); S = zn@zn^T; diag=MASK; /T; nll = -S[i,i^4096] + lse(S[i,:]); mean
// R4: 256x256 lower-triangle tiles, 8 waves, BK=64 stages double-buffered in
// 128KB dynamic LDS. 128B rows + chunk^(row&7) XOR swizzle (R2-proven 0-conflict).
// Fixed-shift logsumexp (logits <= C=1/T) => partials combine via atomicAdd.

#define N 8192
#define D 1024
#define INV_T 14.285714285714286f

typedef __bf16 bf16x8 __attribute__((ext_vector_type(8)));
typedef float f32x4 __attribute__((ext_vector_type(4)));

__device__ inline void gload16(const void* g, void* l) {
  __builtin_amdgcn_global_load_lds(
      (const __attribute__((address_space(1))) void*)g,
      (__attribute__((address_space(3))) void*)l, 16, 0, 0);
}

__device__ inline unsigned short f32_to_bf16(float f) {
  unsigned int u = __float_as_uint(f);
  unsigned int r = (u + 0x7FFFu + ((u >> 16) & 1u)) >> 16;  // RNE
  return (unsigned short)r;
}

// Phase 1: row-normalize z -> bf16 zn; blocks 0..31 also zero rowsum.
__global__ __launch_bounds__(256) void k_normalize(const float* __restrict__ z,
                                                   unsigned short* __restrict__ zn,
                                                   float* __restrict__ rowsum) {
  const int row = blockIdx.x;
  const int t = threadIdx.x;
  if (row < 32) rowsum[row * 256 + t] = 0.0f;
  const float4 v = ((const float4*)(z + (size_t)row * D))[t];
  float ss = v.x * v.x + v.y * v.y + v.z * v.z + v.w * v.w;
#pragma unroll
  for (int off = 32; off > 0; off >>= 1) ss += __shfl_down(ss, off, 64);
  __shared__ float red[4];
  __shared__ float s_inv;
  if ((t & 63) == 0) red[t >> 6] = ss;
  __syncthreads();
  if (t == 0) {
    float tot = red[0] + red[1] + red[2] + red[3];
    s_inv = 1.0f / fmaxf(sqrtf(tot), 1e-8f);
  }
  __syncthreads();
  const float inv = s_inv;
  ushort4 o;
  o.x = f32_to_bf16(v.x * inv);
  o.y = f32_to_bf16(v.y * inv);
  o.z = f32_to_bf16(v.z * inv);
  o.w = f32_to_bf16(v.w * inv);
  ((ushort4*)(zn + (size_t)row * D))[t] = o;
}

// Phase 2: 256x256 lower-triangle tile per block, 512 threads (8 waves, 4x2).
// BK=64: per buffer A 32KB + B 32KB; double-buffered = 128KB dynamic LDS.
// Rows are 128B (8 x 16B chunks); logical chunk c stored at phys chunk c^(r&7)
// -> conflict-free ds_read_b128 (verified 0 conflicts in R2) while keeping
// global_load_lds's forced slot order (base + lane*16).
__global__ __launch_bounds__(512, 2) void k_tile(const unsigned short* __restrict__ zn,
                                                 float* __restrict__ rowsum,
                                                 float* __restrict__ pos) {
  extern __shared__ __align__(16) char smem[];  // 131072
  const int tid = threadIdx.x;
  const int w = tid >> 6, l = tid & 63;

  // decode blockIdx -> lower-triangle (tr, tc), tr >= tc, over 32x32 tile grid
  const int b = blockIdx.x;
  int tr = (int)((sqrtf(8.0f * (float)b + 1.0f) - 1.0f) * 0.5f);
  if (tr * (tr + 1) / 2 > b) --tr;
  if ((tr + 1) * (tr + 2) / 2 <= b) ++tr;
  const int tc = b - tr * (tr + 1) / 2;
  const bool diag = (tr == tc);

  const int wr = w >> 1, wc = w & 1;
  const int m = l & 15, kg = l >> 4;
  const int rowA0 = tr * 256, colB0 = tc * 256;

  f32x4 acc[4][8] = {};

  // staging: per matrix per stage 2048 slots x 16B (256 rows x 8 chunks).
  // slot s -> row s>>3, logical chunk (s&7)^(row&7); phys offset s*16.
  int srow[4], scol[4];
#pragma unroll
  for (int j = 0; j < 4; ++j) {
    int s = j * 512 + tid;
    int r = s >> 3;
    srow[j] = r;
    scol[j] = (s & 7) ^ (r & 7);
  }

  // prologue: stage kt=0 into buffer 0
  {
    char* ab = smem;
    char* bb = smem + 32768;
#pragma unroll
    for (int j = 0; j < 4; ++j) {
      const int s = j * 512 + tid;
      gload16((const char*)zn + ((size_t)(rowA0 + srow[j]) * 2048 + scol[j] * 16), ab + s * 16);
    }
    if (!diag) {
#pragma unroll
      for (int j = 0; j < 4; ++j) {
        const int s = j * 512 + tid;
        gload16((const char*)zn + ((size_t)(colB0 + srow[j]) * 2048 + scol[j] * 16), bb + s * 16);
      }
    }
  }
  __syncthreads();

  for (int kt = 0; kt < 16; ++kt) {
    if (kt < 15) {  // async prefetch kt+1 into other buffer; overlaps MFMA below
      const size_t kb = (size_t)(kt + 1) * 128;
      char* ab = smem + ((kt + 1) & 1) * 65536;
#pragma unroll
      for (int j = 0; j < 4; ++j) {
        const int s = j * 512 + tid;
        gload16((const char*)zn + ((size_t)(rowA0 + srow[j]) * 2048 + kb + scol[j] * 16), ab + s * 16);
      }
      if (!diag) {
        char* bb = ab + 32768;
#pragma unroll
        for (int j = 0; j < 4; ++j) {
          const int s = j * 512 + tid;
          gload16((const char*)zn + ((size_t)(colB0 + srow[j]) * 2048 + kb + scol[j] * 16), bb + s * 16);
        }
      }
    }
    const char* ab = smem + (kt & 1) * 65536;
    const char* bb = diag ? ab : (ab + 32768);
#pragma unroll
    for (int ks = 0; ks < 2; ++ks) {
      bf16x8 af[4], bfr[8];
      const int csw = ((ks * 4 + kg) ^ (m & 7)) * 16;
#pragma unroll
      for (int mt = 0; mt < 4; ++mt)
        af[mt] = *(const bf16x8*)(ab + (wr * 64 + mt * 16 + m) * 128 + csw);
#pragma unroll
      for (int nt = 0; nt < 8; ++nt)
        bfr[nt] = *(const bf16x8*)(bb + (wc * 128 + nt * 16 + m) * 128 + csw);
#pragma unroll
      for (int mt = 0; mt < 4; ++mt)
#pragma unroll
        for (int nt = 0; nt < 8; ++nt)
          acc[mt][nt] = __builtin_amdgcn_mfma_f32_16x16x32_bf16(af[mt], bfr[nt], acc[mt][nt], 0, 0, 0);
    }
    __syncthreads();  // drains prefetch (vmcnt) + guards buffer reuse
  }

  // Epilogue. C/D layout: col=l&15, row=(l>>4)*4+reg.
  const int quad = l >> 4;
  const int col = l & 15;
  float cs[8] = {0.f, 0.f, 0.f, 0.f, 0.f, 0.f, 0.f, 0.f};
#pragma unroll
  for (int mt = 0; mt < 4; ++mt) {
    float rs[4] = {0.f, 0.f, 0.f, 0.f};
#pragma unroll
    for (int nt = 0; nt < 8; ++nt) {
      const int gcol = colB0 + wc * 128 + nt * 16 + col;
#pragma unroll
      for (int r = 0; r < 4; ++r) {
        const int grow = rowA0 + wr * 64 + mt * 16 + quad * 4 + r;
        const float t = acc[mt][nt][r] * INV_T;
        if (gcol == (grow ^ (N / 2))) {  // pos pair; never in diag tiles
          pos[grow] = t;
          pos[gcol] = t;  // S symmetric
        }
        const float e = (gcol == grow) ? 0.0f : __expf(t - INV_T);
        rs[r] += e;
        cs[nt] += e;
      }
    }
#pragma unroll
    for (int off = 1; off < 16; off <<= 1) {
#pragma unroll
      for (int r = 0; r < 4; ++r) rs[r] += __shfl_xor(rs[r], off, 64);
    }
    if (col == 0) {
#pragma unroll
      for (int r = 0; r < 4; ++r)
        atomicAdd(&rowsum[rowA0 + wr * 64 + mt * 16 + quad * 4 + r], rs[r]);
    }
  }
  if (!diag) {  // col sums = row-sums for block tc rows (symmetry)
#pragma unroll
    for (int nt = 0; nt < 8; ++nt) {
      cs[nt] += __shfl_xor(cs[nt], 16, 64);
      cs[nt] += __shfl_xor(cs[nt], 32, 64);
    }
    if (l < 16) {
#pragma unroll
      for (int nt = 0; nt < 8; ++nt)
        atomicAdd(&rowsum[colB0 + wc * 128 + nt * 16 + l], cs[nt]);
    }
  }
}

// Phase 3: single block, no atomics/memset: out = mean(-pos + C + log(rowsum)).
__global__ __launch_bounds__(256) void k_final(const float* __restrict__ rowsum,
                                               const float* __restrict__ pos,
                                               float* __restrict__ out) {
  const int t = threadIdx.x;
  float s = 0.f;
  for (int i = t; i < N; i += 256) s += INV_T + __logf(rowsum[i]) - pos[i];
#pragma unroll
  for (int off = 32; off > 0; off >>= 1) s += __shfl_down(s, off, 64);
  __shared__ float red[4];
  if ((t & 63) == 0) red[t >> 6] = s;
  __syncthreads();
  if (t == 0) out[0] = (red[0] + red[1] + red[2] + red[3]) * (1.0f / N);
}

extern "C" void kernel_launch(void* const* d_in, const int* in_sizes, int n_in,
                              void* d_out, int out_size, void* d_ws, size_t ws_size,
                              hipStream_t stream) {
  const float* z = (const float*)d_in[0];
  float* out = (float*)d_out;
  char* ws = (char*)d_ws;
  unsigned short* zn = (unsigned short*)ws;                       // 16 MiB bf16
  float* rowsum = (float*)(ws + (size_t)N * D * 2);               // 32 KiB
  float* pos = (float*)(ws + (size_t)N * D * 2 + (size_t)N * 4);  // 32 KiB

  static bool attr_set = false;
  if (!attr_set) {  // host-side attribute, idempotent, not a stream op
    hipFuncSetAttribute((const void*)k_tile,
                        hipFuncAttributeMaxDynamicSharedMemorySize, 131072);
    attr_set = true;
  }

  k_normalize<<<N, 256, 0, stream>>>(z, zn, rowsum);
  const int ntiles = (N / 256) * (N / 256 + 1) / 2;  // 528 lower-triangle tiles
  k_tile<<<ntiles, 512, 131072, stream>>>(zn, rowsum, pos);
  k_final<<<1, 256, 0, stream>>>(rowsum, pos, out);
}